// Round 7
// baseline (402.840 us; speedup 1.0000x reference)
//
#include <hip/hip_runtime.h>
#include <hip/hip_bf16.h>

typedef __hip_bfloat16 bf16;
typedef __bf16 bfv8 __attribute__((ext_vector_type(8)));
typedef float f32x4 __attribute__((ext_vector_type(4)));

constexpr int B_     = 16;
constexpr int C_     = 256;   // DIM
constexpr int INNER_ = 512;
constexpr int HEADS_ = 8;
constexpr int DH_    = 64;
constexpr int HW_    = 56;
constexpr int NPIX_  = HW_ * HW_;   // 3136
constexpr int WS_    = 7;
constexpr int WSQ_   = 49;
constexpr int NWIN_  = 64;          // 8x8 windows

// async global->LDS, 16 B per lane (global_load_lds_dwordx4)
static __device__ __forceinline__ void async16(const void* g, void* l) {
    __builtin_amdgcn_global_load_lds(
        (const __attribute__((address_space(1))) unsigned int*)g,
        (__attribute__((address_space(3))) unsigned int*)l, 16, 0, 0);
}

// ---------------------------------------------------------------------------
// Merged setup: [0,2048) cvt of 4 weight mats; [2048,2051) BN-fold; [2051,2059) bias
// ---------------------------------------------------------------------------
__global__ __launch_bounds__(256) void setup_kernel(
    const float* __restrict__ pw0, const float* __restrict__ pw1,
    const float* __restrict__ pw2, const float* __restrict__ pw3,
    bf16* __restrict__ wq,
    const float* __restrict__ dw0, const float* __restrict__ g0,
    const float* __restrict__ b0, const float* __restrict__ m0,
    const float* __restrict__ v0,
    const float* __restrict__ dw1, const float* __restrict__ g1,
    const float* __restrict__ b1, const float* __restrict__ m1,
    const float* __restrict__ v1,
    const float* __restrict__ dw2, const float* __restrict__ g2,
    const float* __restrict__ b2, const float* __restrict__ m2,
    const float* __restrict__ v2,
    float* __restrict__ wf,
    const float* __restrict__ pos, float* __restrict__ biasf) {
    int bx = blockIdx.x;
    if (bx < 2048) {
        int g = bx >> 9;
        const float* s = g == 0 ? pw0 : (g == 1 ? pw1 : (g == 2 ? pw2 : pw3));
        int i = (bx & 511) * 256 + threadIdx.x;
        wq[(size_t)g * (INNER_ * C_) + i] = __float2bfloat16(s[i]);
    } else if (bx < 2051) {
        int p = bx - 2048, c = threadIdx.x;
        const float* dw = p == 0 ? dw0 : (p == 1 ? dw1 : dw2);
        const float* g  = p == 0 ? g0  : (p == 1 ? g1  : g2);
        const float* bb = p == 0 ? b0  : (p == 1 ? b1  : b2);
        const float* mm = p == 0 ? m0  : (p == 1 ? m1  : m2);
        const float* vv = p == 0 ? v0  : (p == 1 ? v1  : v2);
        float s = g[c] * rsqrtf(vv[c] + 1e-5f);
        float* o = wf + (size_t)(p * 256 + c) * 12;
#pragma unroll
        for (int k = 0; k < 9; ++k) o[k] = dw[c * 9 + k] * s;
        o[9] = bb[c] - mm[c] * s;
        o[10] = 0.f; o[11] = 0.f;
    } else {
        int h = bx - 2051;
        int wv = threadIdx.x >> 6, lane = threadIdx.x & 63;
        int quad = lane >> 4, col16 = lane & 15;
        float* dst = biasf + (((size_t)h * 4 + wv) * 64 + lane) * 16;
#pragma unroll
        for (int nt = 0; nt < 4; ++nt)
#pragma unroll
            for (int r = 0; r < 4; ++r) {
                int row = wv * 16 + quad * 4 + r;
                int col = nt * 16 + col16;
                float v;
                if (col >= WSQ_) v = -1e30f;
                else if (row >= WSQ_) v = 0.f;
                else {
                    int xi = row / WS_, yi = row % WS_;
                    int xj = col / WS_, yj = col % WS_;
                    int rel = (xj - xi + 6) * 13 + (yj - yi + 6);
                    v = pos[rel * HEADS_ + h];
                }
                dst[nt * 4 + r] = v;
            }
    }
}

// ---------------------------------------------------------------------------
// Kernel 1: fused dw-conv(3x3)+foldedBN, all 3 projections, LDS-staged.
// ---------------------------------------------------------------------------
__global__ __launch_bounds__(256) void dwbn3_kernel(
    const float* __restrict__ x, const float* __restrict__ wf,
    bf16* __restrict__ tq, bf16* __restrict__ tk, bf16* __restrict__ tv) {
    __shared__ float xs[3 * 64 * 61];   // 46.8 KB
    int y  = blockIdx.x;
    int c0 = blockIdx.y * 64;
    int b  = blockIdx.z;
    int tid = threadIdx.x;
    for (int i = tid; i < 2688; i += 256) {
        int row = i / 896;
        int rem = i - row * 896;
        int ch = rem / 14, s = rem - ch * 14;
        int yy = y + row - 1;
        float4 v4 = make_float4(0.f, 0.f, 0.f, 0.f);
        if (yy >= 0 && yy < HW_)
            v4 = *(const float4*)(x + (size_t)(b * C_ + c0 + ch) * NPIX_
                                    + yy * HW_ + s * 4);
        float* d = xs + (row * 64 + ch) * 61 + 1 + s * 4;
        d[0] = v4.x; d[1] = v4.y; d[2] = v4.z; d[3] = v4.w;
    }
    for (int j = tid; j < 192; j += 256) {
        int row = j >> 6, ch = j & 63;
        xs[(row * 64 + ch) * 61] = 0.f;
        xs[(row * 64 + ch) * 61 + 57] = 0.f;
    }
    __syncthreads();

    int cg = tid & 31, xo = tid >> 5;
    int bcol = xo * 7;
    unsigned int pack[3][7];
#pragma unroll
    for (int ci = 0; ci < 2; ++ci) {
        int ch = cg * 2 + ci;
        float4 w[3][3];
#pragma unroll
        for (int p = 0; p < 3; ++p) {
            const float* wp = wf + (size_t)(p * 256 + c0 + ch) * 12;
            w[p][0] = *(const float4*)(wp);
            w[p][1] = *(const float4*)(wp + 4);
            w[p][2] = *(const float4*)(wp + 8);
        }
        const float* r0 = xs + ch * 61;
        const float* r1 = r0 + 64 * 61;
        const float* r2 = r1 + 64 * 61;
        float a00 = r0[bcol], a01 = r0[bcol + 1];
        float a10 = r1[bcol], a11 = r1[bcol + 1];
        float a20 = r2[bcol], a21 = r2[bcol + 1];
#pragma unroll
        for (int px = 0; px < 7; ++px) {
            float a02 = r0[bcol + px + 2];
            float a12 = r1[bcol + px + 2];
            float a22 = r2[bcol + px + 2];
#pragma unroll
            for (int p = 0; p < 3; ++p) {
                float acc = w[p][2].y
                    + w[p][0].x * a00 + w[p][0].y * a01 + w[p][0].z * a02
                    + w[p][0].w * a10 + w[p][1].x * a11 + w[p][1].y * a12
                    + w[p][1].z * a20 + w[p][1].w * a21 + w[p][2].x * a22;
                bf16 hv = __float2bfloat16(acc);
                unsigned short u; __builtin_memcpy(&u, &hv, 2);
                if (ci == 0) pack[p][px] = u;
                else         pack[p][px] |= ((unsigned int)u) << 16;
            }
            a00 = a01; a01 = a02; a10 = a11; a11 = a12; a20 = a21; a21 = a22;
        }
    }
    bf16* outs[3] = {tq, tk, tv};
    size_t pbase = ((size_t)b * NPIX_ + y * HW_ + bcol) * C_ + c0 + cg * 2;
#pragma unroll
    for (int p = 0; p < 3; ++p)
#pragma unroll
        for (int px = 0; px < 7; ++px)
            *(unsigned int*)(outs[p] + pbase + px * C_) = pack[p][px];
}

// ---------------------------------------------------------------------------
// Kernel 2: qkv pointwise GEMM via MFMA. Tile M=256 pix x N=128 ch, BK=32.
// XCD-swizzled block mapping: the 4 ch-tiles sharing a T pixel-tile get
// linear ids == same (mod 8) -> same XCD -> T fetched once into that L2.
// Q projection (zp==0) pre-scaled by 1/8. Windowed-layout epilogue in 2 halves.
// ---------------------------------------------------------------------------
__global__ __launch_bounds__(256) void gemm_qkv_mfma(
    const bf16* __restrict__ Wbase, const bf16* __restrict__ Tbase,
    bf16* __restrict__ Qbase) {
    __shared__ __align__(16) char smem[128 * 136 * 2];   // 34.8 KB
    bf16* sA = (bf16*)smem;            // 256 pix x 32 k (16 KB)
    bf16* sB = sA + 256 * 32;          // 128 ch  x 32 k (8 KB)
    bf16* sC = (bf16*)smem;            // 128 pix x 136 ch (aliased post-loop)
    int tid = threadIdx.x;
    // ---- XCD swizzle: lin = ((v*4 + ch_t) << 3) + s ; pz = v*8 + s ----
    int lin = blockIdx.x + (blockIdx.y << 2) + blockIdx.z * 52;
    int s  = lin & 7;
    int u  = lin >> 3;
    int ch_t = u & 3;
    int v  = u >> 2;
    int pz = v * 8 + s;                // 0..623 = 13 pix-tiles x 48 z
    int pix_t = pz % 13;
    int z     = pz / 13;
    int zp = z >> 4;                   // projection 0..2
    int b  = z & 15;
    int c0 = ch_t * 128;
    int p0 = pix_t * 256;
    const bf16* W = Wbase + (size_t)zp * (INNER_ * C_);
    const bf16* T = Tbase + (size_t)zp * ((size_t)B_ * NPIX_ * C_);
    bf16* Q = Qbase + (size_t)zp * ((size_t)B_ * INNER_ * NPIX_);
    float qscale = (zp == 0) ? 0.125f : 1.0f;

    int row0 = tid >> 2;               // 0..63
    int kc   = (tid & 3) * 8;
    const bf16* gA[4];
#pragma unroll
    for (int it = 0; it < 4; ++it) {
        int pA = p0 + row0 + it * 64;
        if (pA > NPIX_ - 1) pA = NPIX_ - 1;
        gA[it] = T + ((size_t)b * NPIX_ + pA) * 256 + kc;
    }
    const bf16* gB0 = W + (size_t)(c0 + row0) * 256 + kc;
    const bf16* gB1 = W + (size_t)(c0 + row0 + 64) * 256 + kc;
    char* lA = (char*)sA + tid * 16;
    char* lB = (char*)sB + tid * 16;

    int lane = tid & 63, wv = tid >> 6;
    int wm = (wv >> 1) * 128;          // pixel offset of wave tile (128 rows)
    int wn = (wv & 1) * 64;            // channel offset (64 cols)
    int col16 = lane & 15, quad = lane >> 4;

    f32x4 acc[8][4] = {};
    for (int k0 = 0; k0 < 256; k0 += 32) {
#pragma unroll
        for (int it = 0; it < 4; ++it) {
            async16(gA[it], lA + it * 4096);
            gA[it] += 32;
        }
        async16(gB0, lB);
        async16(gB1, lB + 4096);
        gB0 += 32; gB1 += 32;
        __syncthreads();
        bfv8 af[8], bfr[4];
#pragma unroll
        for (int mt = 0; mt < 8; ++mt)
            af[mt] = *(const bfv8*)(sA + (wm + mt * 16 + col16) * 32 + quad * 8);
#pragma unroll
        for (int nt = 0; nt < 4; ++nt)
            bfr[nt] = *(const bfv8*)(sB + (wn + nt * 16 + col16) * 32 + quad * 8);
#pragma unroll
        for (int mt = 0; mt < 8; ++mt)
#pragma unroll
            for (int nt = 0; nt < 4; ++nt)
                acc[mt][nt] = __builtin_amdgcn_mfma_f32_16x16x32_bf16(
                    af[mt], bfr[nt], acc[mt][nt], 0, 0, 0);
        __syncthreads();
    }
    // epilogue in two 128-pixel halves through sC
#pragma unroll
    for (int h2 = 0; h2 < 2; ++h2) {
        if ((wv >> 1) == h2) {
#pragma unroll
            for (int mt = 0; mt < 8; ++mt)
#pragma unroll
                for (int nt = 0; nt < 4; ++nt) {
                    f32x4 a = acc[mt][nt];
#pragma unroll
                    for (int r = 0; r < 4; ++r)
                        sC[(mt * 16 + quad * 4 + r) * 136 + wn + nt * 16 + col16] =
                            __float2bfloat16(a[r] * qscale);
                }
        }
        __syncthreads();
#pragma unroll
        for (int j = 0; j < 8; ++j) {
            int lin2 = j * 256 + tid;      // 128 pix x 16 ch-groups
            int pixl = lin2 >> 4, chg = lin2 & 15;
            int p = p0 + h2 * 128 + pixl;
            if (p < NPIX_) {
                int ch = c0 + chg * 8;
                int h = ch >> 6, d = ch & 63;
                int yy = p / HW_, xx = p % HW_;
                int wdw = (yy / WS_) * 8 + (xx / WS_);
                int j49 = (yy % WS_) * WS_ + (xx % WS_);
                bfv8 vd = *(const bfv8*)(sC + pixl * 136 + chg * 8);
                *(bfv8*)(Q + ((((size_t)b * HEADS_ + h) * NWIN_ + wdw) * WSQ_ + j49) * DH_ + d) = vd;
            }
        }
        __syncthreads();
    }
}

// ---------------------------------------------------------------------------
// Kernel 3: windowed attention via MFMA. One block (4 waves) per (b,h,window).
// ---------------------------------------------------------------------------
__global__ __launch_bounds__(256) void attn_mfma(
    const bf16* __restrict__ Q, const bf16* __restrict__ Kt,
    const bf16* __restrict__ V, const float* __restrict__ biasf,
    bf16* __restrict__ O) {
    __shared__ __align__(16) bf16 qs[64 * 72];   // aliased by ps after barrier 2
    __shared__ __align__(16) bf16 ks[64 * 72];
    __shared__ __align__(16) bf16 vt[64 * 72];   // V^T: [d][j]
    bf16* ps = qs;
    int tid = threadIdx.x;
    int w = blockIdx.x & 63;
    int h = (blockIdx.x >> 6) & 7;
    int b = blockIdx.x >> 9;
    size_t base = (((size_t)b * HEADS_ + h) * NWIN_ + w) * (WSQ_ * DH_);

    {
        bfv8 z = {};
#pragma unroll
        for (int it = 0; it < 2; ++it) {
            int c = it * 256 + tid;
            int row = c >> 3, col = (c & 7) * 8;
            bfv8 vq = z, vk = z;
            if (c < 392) {
                vq = *(const bfv8*)(Q + base + c * 8);
                vk = *(const bfv8*)(Kt + base + c * 8);
            }
            *(bfv8*)(qs + row * 72 + col) = vq;
            *(bfv8*)(ks + row * 72 + col) = vk;
        }
#pragma unroll
        for (int it = 0; it < 2; ++it) {
            int idx = it * 256 + tid;
            int d = idx & 63, j8 = idx >> 6;
            bf16 val[8];
            if (j8 < 6) {
#pragma unroll
                for (int u = 0; u < 8; ++u)
                    val[u] = V[base + (j8 * 8 + u) * 64 + d];
            } else {
#pragma unroll
                for (int u = 0; u < 8; ++u) {
                    int j = j8 * 8 + u;
                    val[u] = (j < WSQ_) ? V[base + j * 64 + d]
                                        : __float2bfloat16(0.f);
                }
            }
            *(bfv8*)(vt + d * 72 + j8 * 8) = *(const bfv8*)val;
        }
    }
    __syncthreads();

    int lane = tid & 63, wv = tid >> 6;
    int band = wv * 16;
    int col16 = lane & 15, quad = lane >> 4;

    bfv8 aq0 = *(const bfv8*)(qs + (band + col16) * 72 + quad * 8);
    bfv8 aq1 = *(const bfv8*)(qs + (band + col16) * 72 + 32 + quad * 8);
    bfv8 bk[4][2];
#pragma unroll
    for (int nt = 0; nt < 4; ++nt) {
        bk[nt][0] = *(const bfv8*)(ks + (nt * 16 + col16) * 72 + quad * 8);
        bk[nt][1] = *(const bfv8*)(ks + (nt * 16 + col16) * 72 + 32 + quad * 8);
    }
    __syncthreads();   // qs/ks dead; ps (== qs) may be written

    const float* bp = biasf + (((size_t)h * 4 + wv) * 64 + lane) * 16;
    f32x4 sacc[4];
#pragma unroll
    for (int nt = 0; nt < 4; ++nt) {
        sacc[nt] = *(const f32x4*)(bp + nt * 4);
        sacc[nt] = __builtin_amdgcn_mfma_f32_16x16x32_bf16(aq0, bk[nt][0], sacc[nt], 0, 0, 0);
        sacc[nt] = __builtin_amdgcn_mfma_f32_16x16x32_bf16(aq1, bk[nt][1], sacc[nt], 0, 0, 0);
    }
    float p[4][4];
    float inv[4];
#pragma unroll
    for (int r = 0; r < 4; ++r) {
        float s0 = sacc[0][r], s1 = sacc[1][r], s2 = sacc[2][r], s3 = sacc[3][r];
        float mx = fmaxf(fmaxf(s0, s1), fmaxf(s2, s3));
        mx = fmaxf(mx, __shfl_xor(mx, 1, 16));
        mx = fmaxf(mx, __shfl_xor(mx, 2, 16));
        mx = fmaxf(mx, __shfl_xor(mx, 4, 16));
        mx = fmaxf(mx, __shfl_xor(mx, 8, 16));
        float e0 = __expf(s0 - mx), e1 = __expf(s1 - mx);
        float e2 = __expf(s2 - mx), e3 = __expf(s3 - mx);
        float sm = e0 + e1 + e2 + e3;
        sm += __shfl_xor(sm, 1, 16);
        sm += __shfl_xor(sm, 2, 16);
        sm += __shfl_xor(sm, 4, 16);
        sm += __shfl_xor(sm, 8, 16);
        p[0][r] = e0; p[1][r] = e1; p[2][r] = e2; p[3][r] = e3;
        inv[r] = 1.f / sm;
    }
#pragma unroll
    for (int nt = 0; nt < 4; ++nt)
#pragma unroll
        for (int r = 0; r < 4; ++r)
            ps[(band + quad * 4 + r) * 72 + nt * 16 + col16] = __float2bfloat16(p[nt][r]);
    f32x4 oacc[4] = {};
    bfv8 ap0 = *(const bfv8*)(ps + (band + col16) * 72 + quad * 8);
    bfv8 ap1 = *(const bfv8*)(ps + (band + col16) * 72 + 32 + quad * 8);
#pragma unroll
    for (int nt = 0; nt < 4; ++nt) {
        bfv8 bv0 = *(const bfv8*)(vt + (nt * 16 + col16) * 72 + quad * 8);
        bfv8 bv1 = *(const bfv8*)(vt + (nt * 16 + col16) * 72 + 32 + quad * 8);
        oacc[nt] = __builtin_amdgcn_mfma_f32_16x16x32_bf16(ap0, bv0, oacc[nt], 0, 0, 0);
        oacc[nt] = __builtin_amdgcn_mfma_f32_16x16x32_bf16(ap1, bv1, oacc[nt], 0, 0, 0);
    }
    int wy = w >> 3, wx = w & 7;
#pragma unroll
    for (int r = 0; r < 4; ++r) {
        int i = band + quad * 4 + r;
        if (i < WSQ_) {
            int py = wy * WS_ + i / WS_, px = wx * WS_ + i % WS_;
            size_t ob = ((size_t)b * NPIX_ + py * HW_ + px) * INNER_ + h * DH_;
            float sc = inv[r];
#pragma unroll
            for (int nt = 0; nt < 4; ++nt)
                O[ob + nt * 16 + col16] = __float2bfloat16(oacc[nt][r] * sc);
        }
    }
}

// ---------------------------------------------------------------------------
// Kernel 4: output pointwise GEMM via MFMA + bias (fp32 out).
// ---------------------------------------------------------------------------
__global__ __launch_bounds__(256) void gemm_out_mfma(
    const bf16* __restrict__ W, const bf16* __restrict__ O,
    const float* __restrict__ bias, float* __restrict__ out) {
    __shared__ __align__(16) bf16 sA[128 * 32];
    __shared__ __align__(16) bf16 sB[128 * 32];
    int tid = threadIdx.x;
    int c0 = blockIdx.x * 128;
    int p0 = blockIdx.y * 128;
    int b  = blockIdx.z;

    int row0 = tid >> 2;
    int kc   = (tid & 3) * 8;
    int pB0 = p0 + row0;       if (pB0 > NPIX_ - 1) pB0 = NPIX_ - 1;
    int pB1 = p0 + row0 + 64;  if (pB1 > NPIX_ - 1) pB1 = NPIX_ - 1;
    const bf16* gA0 = W + (size_t)(c0 + row0) * 512 + kc;
    const bf16* gA1 = W + (size_t)(c0 + row0 + 64) * 512 + kc;
    const bf16* gB0 = O + ((size_t)b * NPIX_ + pB0) * 512 + kc;
    const bf16* gB1 = O + ((size_t)b * NPIX_ + pB1) * 512 + kc;
    char* lA = (char*)sA + tid * 16;
    char* lB = (char*)sB + tid * 16;

    int lane = tid & 63, wv = tid >> 6;
    int wm = (wv >> 1) * 64;
    int wn = (wv & 1) * 64;
    int col16 = lane & 15, quad = lane >> 4;

    f32x4 acc[4][4] = {};
    for (int k0 = 0; k0 < 512; k0 += 32) {
        async16(gA0, lA);
        async16(gA1, lA + 4096);
        async16(gB0, lB);
        async16(gB1, lB + 4096);
        gA0 += 32; gA1 += 32; gB0 += 32; gB1 += 32;
        __syncthreads();
        bfv8 af[4], bfr[4];
#pragma unroll
        for (int mt = 0; mt < 4; ++mt)
            af[mt] = *(const bfv8*)(sA + (wm + mt * 16 + col16) * 32 + quad * 8);
#pragma unroll
        for (int nt = 0; nt < 4; ++nt)
            bfr[nt] = *(const bfv8*)(sB + (wn + nt * 16 + col16) * 32 + quad * 8);
#pragma unroll
        for (int mt = 0; mt < 4; ++mt)
#pragma unroll
            for (int nt = 0; nt < 4; ++nt)
                acc[mt][nt] = __builtin_amdgcn_mfma_f32_16x16x32_bf16(
                    af[mt], bfr[nt], acc[mt][nt], 0, 0, 0);
        __syncthreads();
    }
#pragma unroll
    for (int mt = 0; mt < 4; ++mt) {
#pragma unroll
        for (int r = 0; r < 4; ++r) {
            int ch = c0 + wm + mt * 16 + quad * 4 + r;
            float bc = bias[ch];
#pragma unroll
            for (int nt = 0; nt < 4; ++nt) {
                int p = p0 + wn + nt * 16 + col16;
                if (p < NPIX_)
                    out[((size_t)b * C_ + ch) * NPIX_ + p] = acc[mt][nt][r] + bc;
            }
        }
    }
}

// ---------------------------------------------------------------------------
extern "C" void kernel_launch(void* const* d_in, const int* in_sizes, int n_in,
                              void* d_out, int out_size, void* d_ws, size_t ws_size,
                              hipStream_t stream) {
    (void)in_sizes; (void)n_in; (void)out_size; (void)ws_size;
    const float* x     = (const float*)d_in[0];
    const float* pos   = (const float*)d_in[19];
    const float* out_w = (const float*)d_in[20];
    const float* out_b = (const float*)d_in[21];

    size_t tElems = (size_t)B_ * NPIX_ * C_;        // 12.845M
    size_t qElems = (size_t)B_ * INNER_ * NPIX_;    // 25.69M
    bf16* tq = (bf16*)d_ws;                         // t's: [3][B][pix][256]
    bf16* q  = tq + 3 * tElems;                     // qkv: [3][B][h][w][49][64]
    bf16* o  = tq;                                  // aliases tq+tk (dead by attn)
    float* wf = (float*)(q + 3 * qElems);           // [3][256][12] fp32
    bf16* wq = (bf16*)(wf + 3 * 256 * 12);          // [4][512*256] bf16 weights
    bf16* wo = wq + 3 * (INNER_ * C_);
    float* biasf = (float*)(wo + C_ * INNER_);      // [8][4][64][16] fp32

    dim3 blk(256);
    dim3 gDw(HW_, 4, B_);                           // 56 x 4 x 16
    dim3 gQkv(4, 13, 48);                           // swizzled in-kernel
    dim3 gOut(C_ / 128, 25, B_);

    setup_kernel<<<2059, blk, 0, stream>>>(
        (const float*)d_in[6], (const float*)d_in[12], (const float*)d_in[18],
        out_w, wq,
        (const float*)d_in[1],  (const float*)d_in[2],  (const float*)d_in[3],
        (const float*)d_in[4],  (const float*)d_in[5],
        (const float*)d_in[7],  (const float*)d_in[8],  (const float*)d_in[9],
        (const float*)d_in[10], (const float*)d_in[11],
        (const float*)d_in[13], (const float*)d_in[14], (const float*)d_in[15],
        (const float*)d_in[16], (const float*)d_in[17], wf,
        pos, biasf);

    dwbn3_kernel<<<gDw, blk, 0, stream>>>(x, wf, tq, tq + tElems, tq + 2 * tElems);
    gemm_qkv_mfma<<<gQkv, blk, 0, stream>>>(wq, tq, q);
    attn_mfma<<<B_ * HEADS_ * NWIN_, blk, 0, stream>>>(
        q, q + qElems, q + 2 * qElems, biasf, o);
    gemm_out_mfma<<<gOut, blk, 0, stream>>>(wo, o, out_b, (float*)d_out);
}

// Round 8
// 336.820 us; speedup vs baseline: 1.1960x; 1.1960x over previous
//
#include <hip/hip_runtime.h>
#include <hip/hip_bf16.h>

typedef __hip_bfloat16 bf16;
typedef __bf16 bfv8 __attribute__((ext_vector_type(8)));
typedef float f32x4 __attribute__((ext_vector_type(4)));

constexpr int B_     = 16;
constexpr int C_     = 256;   // DIM
constexpr int INNER_ = 512;
constexpr int HEADS_ = 8;
constexpr int DH_    = 64;
constexpr int HW_    = 56;
constexpr int NPIX_  = HW_ * HW_;   // 3136
constexpr int WS_    = 7;
constexpr int WSQ_   = 49;
constexpr int NWIN_  = 64;          // 8x8 windows

// async global->LDS, 16 B per lane (global_load_lds_dwordx4)
static __device__ __forceinline__ void async16(const void* g, void* l) {
    __builtin_amdgcn_global_load_lds(
        (const __attribute__((address_space(1))) unsigned int*)g,
        (__attribute__((address_space(3))) unsigned int*)l, 16, 0, 0);
}

// ---------------------------------------------------------------------------
// Merged setup: [0,2048) cvt of 4 weight mats; [2048,2051) BN-fold; [2051,2059) bias
// ---------------------------------------------------------------------------
__global__ __launch_bounds__(256) void setup_kernel(
    const float* __restrict__ pw0, const float* __restrict__ pw1,
    const float* __restrict__ pw2, const float* __restrict__ pw3,
    bf16* __restrict__ wq,
    const float* __restrict__ dw0, const float* __restrict__ g0,
    const float* __restrict__ b0, const float* __restrict__ m0,
    const float* __restrict__ v0,
    const float* __restrict__ dw1, const float* __restrict__ g1,
    const float* __restrict__ b1, const float* __restrict__ m1,
    const float* __restrict__ v1,
    const float* __restrict__ dw2, const float* __restrict__ g2,
    const float* __restrict__ b2, const float* __restrict__ m2,
    const float* __restrict__ v2,
    float* __restrict__ wf,
    const float* __restrict__ pos, float* __restrict__ biasf) {
    int bx = blockIdx.x;
    if (bx < 2048) {
        int g = bx >> 9;
        const float* s = g == 0 ? pw0 : (g == 1 ? pw1 : (g == 2 ? pw2 : pw3));
        int i = (bx & 511) * 256 + threadIdx.x;
        wq[(size_t)g * (INNER_ * C_) + i] = __float2bfloat16(s[i]);
    } else if (bx < 2051) {
        int p = bx - 2048, c = threadIdx.x;
        const float* dw = p == 0 ? dw0 : (p == 1 ? dw1 : dw2);
        const float* g  = p == 0 ? g0  : (p == 1 ? g1  : g2);
        const float* bb = p == 0 ? b0  : (p == 1 ? b1  : b2);
        const float* mm = p == 0 ? m0  : (p == 1 ? m1  : m2);
        const float* vv = p == 0 ? v0  : (p == 1 ? v1  : v2);
        float s = g[c] * rsqrtf(vv[c] + 1e-5f);
        float* o = wf + (size_t)(p * 256 + c) * 12;
#pragma unroll
        for (int k = 0; k < 9; ++k) o[k] = dw[c * 9 + k] * s;
        o[9] = bb[c] - mm[c] * s;
        o[10] = 0.f; o[11] = 0.f;
    } else {
        int h = bx - 2051;
        int wv = threadIdx.x >> 6, lane = threadIdx.x & 63;
        int quad = lane >> 4, col16 = lane & 15;
        float* dst = biasf + (((size_t)h * 4 + wv) * 64 + lane) * 16;
#pragma unroll
        for (int nt = 0; nt < 4; ++nt)
#pragma unroll
            for (int r = 0; r < 4; ++r) {
                int row = wv * 16 + quad * 4 + r;
                int col = nt * 16 + col16;
                float v;
                if (col >= WSQ_) v = -1e30f;
                else if (row >= WSQ_) v = 0.f;
                else {
                    int xi = row / WS_, yi = row % WS_;
                    int xj = col / WS_, yj = col % WS_;
                    int rel = (xj - xi + 6) * 13 + (yj - yi + 6);
                    v = pos[rel * HEADS_ + h];
                }
                dst[nt * 4 + r] = v;
            }
    }
}

// ---------------------------------------------------------------------------
// Kernel 1: fused dw-conv(3x3)+foldedBN, all 3 projections, LDS-staged.
// ---------------------------------------------------------------------------
__global__ __launch_bounds__(256) void dwbn3_kernel(
    const float* __restrict__ x, const float* __restrict__ wf,
    bf16* __restrict__ tq, bf16* __restrict__ tk, bf16* __restrict__ tv) {
    __shared__ float xs[3 * 64 * 61];   // 46.8 KB
    int y  = blockIdx.x;
    int c0 = blockIdx.y * 64;
    int b  = blockIdx.z;
    int tid = threadIdx.x;
    for (int i = tid; i < 2688; i += 256) {
        int row = i / 896;
        int rem = i - row * 896;
        int ch = rem / 14, s = rem - ch * 14;
        int yy = y + row - 1;
        float4 v4 = make_float4(0.f, 0.f, 0.f, 0.f);
        if (yy >= 0 && yy < HW_)
            v4 = *(const float4*)(x + (size_t)(b * C_ + c0 + ch) * NPIX_
                                    + yy * HW_ + s * 4);
        float* d = xs + (row * 64 + ch) * 61 + 1 + s * 4;
        d[0] = v4.x; d[1] = v4.y; d[2] = v4.z; d[3] = v4.w;
    }
    for (int j = tid; j < 192; j += 256) {
        int row = j >> 6, ch = j & 63;
        xs[(row * 64 + ch) * 61] = 0.f;
        xs[(row * 64 + ch) * 61 + 57] = 0.f;
    }
    __syncthreads();

    int cg = tid & 31, xo = tid >> 5;
    int bcol = xo * 7;
    unsigned int pack[3][7];
#pragma unroll
    for (int ci = 0; ci < 2; ++ci) {
        int ch = cg * 2 + ci;
        float4 w[3][3];
#pragma unroll
        for (int p = 0; p < 3; ++p) {
            const float* wp = wf + (size_t)(p * 256 + c0 + ch) * 12;
            w[p][0] = *(const float4*)(wp);
            w[p][1] = *(const float4*)(wp + 4);
            w[p][2] = *(const float4*)(wp + 8);
        }
        const float* r0 = xs + ch * 61;
        const float* r1 = r0 + 64 * 61;
        const float* r2 = r1 + 64 * 61;
        float a00 = r0[bcol], a01 = r0[bcol + 1];
        float a10 = r1[bcol], a11 = r1[bcol + 1];
        float a20 = r2[bcol], a21 = r2[bcol + 1];
#pragma unroll
        for (int px = 0; px < 7; ++px) {
            float a02 = r0[bcol + px + 2];
            float a12 = r1[bcol + px + 2];
            float a22 = r2[bcol + px + 2];
#pragma unroll
            for (int p = 0; p < 3; ++p) {
                float acc = w[p][2].y
                    + w[p][0].x * a00 + w[p][0].y * a01 + w[p][0].z * a02
                    + w[p][0].w * a10 + w[p][1].x * a11 + w[p][1].y * a12
                    + w[p][1].z * a20 + w[p][1].w * a21 + w[p][2].x * a22;
                bf16 hv = __float2bfloat16(acc);
                unsigned short u; __builtin_memcpy(&u, &hv, 2);
                if (ci == 0) pack[p][px] = u;
                else         pack[p][px] |= ((unsigned int)u) << 16;
            }
            a00 = a01; a01 = a02; a10 = a11; a11 = a12; a20 = a21; a21 = a22;
        }
    }
    bf16* outs[3] = {tq, tk, tv};
    size_t pbase = ((size_t)b * NPIX_ + y * HW_ + bcol) * C_ + c0 + cg * 2;
#pragma unroll
    for (int p = 0; p < 3; ++p)
#pragma unroll
        for (int px = 0; px < 7; ++px)
            *(unsigned int*)(outs[p] + pbase + px * C_) = pack[p][px];
}

// ---------------------------------------------------------------------------
// Kernel 2: qkv pointwise GEMM via MFMA. Tile 128 pix x 128 ch (R6 structure)
// + XCD swizzle: the 4 ch-tiles sharing a T pixel-tile get linear ids with the
// same (mod 8) -> same XCD -> T fetched once into that XCD's L2.
// Q projection (zp==0) pre-scaled by 1/8. Windowed-layout epilogue.
// ---------------------------------------------------------------------------
__global__ __launch_bounds__(256) void gemm_qkv_mfma(
    const bf16* __restrict__ Wbase, const bf16* __restrict__ Tbase,
    bf16* __restrict__ Qbase) {
    __shared__ __align__(16) char smem[128 * 136 * 2];
    bf16* sA = (bf16*)smem;            // 128 pix x 32 k
    bf16* sB = sA + 128 * 32;          // 128 ch  x 32 k
    bf16* sC = (bf16*)smem;            // 128 pix x 136 ch (aliased post-loop)
    int tid = threadIdx.x;
    // XCD swizzle decode: lin = ((v*4 + ch_t) << 3) + s ; pz = v*8 + s
    int lin = blockIdx.x + (blockIdx.y << 2) + blockIdx.z * 100;
    int s  = lin & 7;
    int u  = lin >> 3;                 // 0..599
    int ch_t = u & 3;
    int v  = u >> 2;                   // 0..149
    int pz = v * 8 + s;                // 0..1199 = 25 pix-tiles x 48 z
    int pix_t = pz % 25;
    int z     = pz / 25;
    int zp = z >> 4;                   // projection 0..2
    int b  = z & 15;
    int c0 = ch_t * 128;
    int p0 = pix_t * 128;
    const bf16* W = Wbase + (size_t)zp * (INNER_ * C_);
    const bf16* T = Tbase + (size_t)zp * ((size_t)B_ * NPIX_ * C_);
    bf16* Q = Qbase + (size_t)zp * ((size_t)B_ * INNER_ * NPIX_);
    float qscale = (zp == 0) ? 0.125f : 1.0f;

    int row0 = tid >> 2;
    int kc   = (tid & 3) * 8;
    int pA0 = p0 + row0;       if (pA0 > NPIX_ - 1) pA0 = NPIX_ - 1;
    int pA1 = p0 + row0 + 64;  if (pA1 > NPIX_ - 1) pA1 = NPIX_ - 1;
    const bf16* gA0 = T + ((size_t)b * NPIX_ + pA0) * 256 + kc;
    const bf16* gA1 = T + ((size_t)b * NPIX_ + pA1) * 256 + kc;
    const bf16* gB0 = W + (size_t)(c0 + row0) * 256 + kc;
    const bf16* gB1 = W + (size_t)(c0 + row0 + 64) * 256 + kc;
    char* lA = (char*)sA + tid * 16;
    char* lB = (char*)sB + tid * 16;

    int lane = tid & 63, wv = tid >> 6;
    int wm = (wv >> 1) * 64;
    int wn = (wv & 1) * 64;
    int col16 = lane & 15, quad = lane >> 4;

    f32x4 acc[4][4] = {};
    for (int k0 = 0; k0 < 256; k0 += 32) {
        async16(gA0, lA);
        async16(gA1, lA + 4096);
        async16(gB0, lB);
        async16(gB1, lB + 4096);
        gA0 += 32; gA1 += 32; gB0 += 32; gB1 += 32;
        __syncthreads();
        bfv8 af[4], bfr[4];
#pragma unroll
        for (int mt = 0; mt < 4; ++mt)
            af[mt] = *(const bfv8*)(sA + (wm + mt * 16 + col16) * 32 + quad * 8);
#pragma unroll
        for (int nt = 0; nt < 4; ++nt)
            bfr[nt] = *(const bfv8*)(sB + (wn + nt * 16 + col16) * 32 + quad * 8);
#pragma unroll
        for (int mt = 0; mt < 4; ++mt)
#pragma unroll
            for (int nt = 0; nt < 4; ++nt)
                acc[mt][nt] = __builtin_amdgcn_mfma_f32_16x16x32_bf16(
                    af[mt], bfr[nt], acc[mt][nt], 0, 0, 0);
        __syncthreads();
    }
#pragma unroll
    for (int mt = 0; mt < 4; ++mt)
#pragma unroll
        for (int nt = 0; nt < 4; ++nt) {
            f32x4 a = acc[mt][nt];
#pragma unroll
            for (int r = 0; r < 4; ++r)
                sC[(wm + mt * 16 + quad * 4 + r) * 136 + wn + nt * 16 + col16] =
                    __float2bfloat16(a[r] * qscale);
        }
    __syncthreads();
#pragma unroll
    for (int j = 0; j < 8; ++j) {
        int lin2 = j * 256 + tid;
        int pixl = lin2 >> 4, chg = lin2 & 15;
        int p = p0 + pixl;
        if (p < NPIX_) {
            int ch = c0 + chg * 8;
            int h = ch >> 6, d = ch & 63;
            int yy = p / HW_, xx = p % HW_;
            int wdw = (yy / WS_) * 8 + (xx / WS_);
            int j49 = (yy % WS_) * WS_ + (xx % WS_);
            bfv8 vd = *(const bfv8*)(sC + pixl * 136 + chg * 8);
            *(bfv8*)(Q + ((((size_t)b * HEADS_ + h) * NWIN_ + wdw) * WSQ_ + j49) * DH_ + d) = vd;
        }
    }
}

// ---------------------------------------------------------------------------
// Kernel 3: windowed attention via MFMA. One block (4 waves) per (b,h,window).
// ---------------------------------------------------------------------------
__global__ __launch_bounds__(256) void attn_mfma(
    const bf16* __restrict__ Q, const bf16* __restrict__ Kt,
    const bf16* __restrict__ V, const float* __restrict__ biasf,
    bf16* __restrict__ O) {
    __shared__ __align__(16) bf16 qs[64 * 72];   // aliased by ps after barrier 2
    __shared__ __align__(16) bf16 ks[64 * 72];
    __shared__ __align__(16) bf16 vt[64 * 72];   // V^T: [d][j]
    bf16* ps = qs;
    int tid = threadIdx.x;
    int w = blockIdx.x & 63;
    int h = (blockIdx.x >> 6) & 7;
    int b = blockIdx.x >> 9;
    size_t base = (((size_t)b * HEADS_ + h) * NWIN_ + w) * (WSQ_ * DH_);

    {
        bfv8 z = {};
#pragma unroll
        for (int it = 0; it < 2; ++it) {
            int c = it * 256 + tid;
            int row = c >> 3, col = (c & 7) * 8;
            bfv8 vq = z, vk = z;
            if (c < 392) {
                vq = *(const bfv8*)(Q + base + c * 8);
                vk = *(const bfv8*)(Kt + base + c * 8);
            }
            *(bfv8*)(qs + row * 72 + col) = vq;
            *(bfv8*)(ks + row * 72 + col) = vk;
        }
#pragma unroll
        for (int it = 0; it < 2; ++it) {
            int idx = it * 256 + tid;
            int d = idx & 63, j8 = idx >> 6;
            bf16 val[8];
            if (j8 < 6) {
#pragma unroll
                for (int u = 0; u < 8; ++u)
                    val[u] = V[base + (j8 * 8 + u) * 64 + d];
            } else {
#pragma unroll
                for (int u = 0; u < 8; ++u) {
                    int j = j8 * 8 + u;
                    val[u] = (j < WSQ_) ? V[base + j * 64 + d]
                                        : __float2bfloat16(0.f);
                }
            }
            *(bfv8*)(vt + d * 72 + j8 * 8) = *(const bfv8*)val;
        }
    }
    __syncthreads();

    int lane = tid & 63, wv = tid >> 6;
    int band = wv * 16;
    int col16 = lane & 15, quad = lane >> 4;

    bfv8 aq0 = *(const bfv8*)(qs + (band + col16) * 72 + quad * 8);
    bfv8 aq1 = *(const bfv8*)(qs + (band + col16) * 72 + 32 + quad * 8);
    bfv8 bk[4][2];
#pragma unroll
    for (int nt = 0; nt < 4; ++nt) {
        bk[nt][0] = *(const bfv8*)(ks + (nt * 16 + col16) * 72 + quad * 8);
        bk[nt][1] = *(const bfv8*)(ks + (nt * 16 + col16) * 72 + 32 + quad * 8);
    }
    __syncthreads();   // qs/ks dead; ps (== qs) may be written

    const float* bp = biasf + (((size_t)h * 4 + wv) * 64 + lane) * 16;
    f32x4 sacc[4];
#pragma unroll
    for (int nt = 0; nt < 4; ++nt) {
        sacc[nt] = *(const f32x4*)(bp + nt * 4);
        sacc[nt] = __builtin_amdgcn_mfma_f32_16x16x32_bf16(aq0, bk[nt][0], sacc[nt], 0, 0, 0);
        sacc[nt] = __builtin_amdgcn_mfma_f32_16x16x32_bf16(aq1, bk[nt][1], sacc[nt], 0, 0, 0);
    }
    float p[4][4];
    float inv[4];
#pragma unroll
    for (int r = 0; r < 4; ++r) {
        float s0 = sacc[0][r], s1 = sacc[1][r], s2 = sacc[2][r], s3 = sacc[3][r];
        float mx = fmaxf(fmaxf(s0, s1), fmaxf(s2, s3));
        mx = fmaxf(mx, __shfl_xor(mx, 1, 16));
        mx = fmaxf(mx, __shfl_xor(mx, 2, 16));
        mx = fmaxf(mx, __shfl_xor(mx, 4, 16));
        mx = fmaxf(mx, __shfl_xor(mx, 8, 16));
        float e0 = __expf(s0 - mx), e1 = __expf(s1 - mx);
        float e2 = __expf(s2 - mx), e3 = __expf(s3 - mx);
        float sm = e0 + e1 + e2 + e3;
        sm += __shfl_xor(sm, 1, 16);
        sm += __shfl_xor(sm, 2, 16);
        sm += __shfl_xor(sm, 4, 16);
        sm += __shfl_xor(sm, 8, 16);
        p[0][r] = e0; p[1][r] = e1; p[2][r] = e2; p[3][r] = e3;
        inv[r] = 1.f / sm;
    }
#pragma unroll
    for (int nt = 0; nt < 4; ++nt)
#pragma unroll
        for (int r = 0; r < 4; ++r)
            ps[(band + quad * 4 + r) * 72 + nt * 16 + col16] = __float2bfloat16(p[nt][r]);
    f32x4 oacc[4] = {};
    bfv8 ap0 = *(const bfv8*)(ps + (band + col16) * 72 + quad * 8);
    bfv8 ap1 = *(const bfv8*)(ps + (band + col16) * 72 + 32 + quad * 8);
#pragma unroll
    for (int nt = 0; nt < 4; ++nt) {
        bfv8 bv0 = *(const bfv8*)(vt + (nt * 16 + col16) * 72 + quad * 8);
        bfv8 bv1 = *(const bfv8*)(vt + (nt * 16 + col16) * 72 + 32 + quad * 8);
        oacc[nt] = __builtin_amdgcn_mfma_f32_16x16x32_bf16(ap0, bv0, oacc[nt], 0, 0, 0);
        oacc[nt] = __builtin_amdgcn_mfma_f32_16x16x32_bf16(ap1, bv1, oacc[nt], 0, 0, 0);
    }
    int wy = w >> 3, wx = w & 7;
#pragma unroll
    for (int r = 0; r < 4; ++r) {
        int i = band + quad * 4 + r;
        if (i < WSQ_) {
            int py = wy * WS_ + i / WS_, px = wx * WS_ + i % WS_;
            size_t ob = ((size_t)b * NPIX_ + py * HW_ + px) * INNER_ + h * DH_;
            float sc = inv[r];
#pragma unroll
            for (int nt = 0; nt < 4; ++nt)
                O[ob + nt * 16 + col16] = __float2bfloat16(oacc[nt][r] * sc);
        }
    }
}

// ---------------------------------------------------------------------------
// Kernel 4: output pointwise GEMM via MFMA + bias (fp32 out), XCD-swizzled.
// ---------------------------------------------------------------------------
__global__ __launch_bounds__(256) void gemm_out_mfma(
    const bf16* __restrict__ W, const bf16* __restrict__ O,
    const float* __restrict__ bias, float* __restrict__ out) {
    __shared__ __align__(16) bf16 sA[128 * 32];
    __shared__ __align__(16) bf16 sB[128 * 32];
    int tid = threadIdx.x;
    // XCD swizzle: 2 ch-tiles sharing an O pixel-tile -> same XCD
    int lin = blockIdx.x + (blockIdx.y << 1) + blockIdx.z * 50;
    int s  = lin & 7;
    int u  = lin >> 3;                 // 0..99
    int ch_t = u & 1;
    int v  = u >> 1;                   // 0..49
    int pz = v * 8 + s;                // 0..399 = 25 pix-tiles x 16 b
    int pix_t = pz % 25;
    int b     = pz / 25;
    int c0 = ch_t * 128;
    int p0 = pix_t * 128;

    int row0 = tid >> 2;
    int kc   = (tid & 3) * 8;
    int pB0 = p0 + row0;       if (pB0 > NPIX_ - 1) pB0 = NPIX_ - 1;
    int pB1 = p0 + row0 + 64;  if (pB1 > NPIX_ - 1) pB1 = NPIX_ - 1;
    const bf16* gA0 = W + (size_t)(c0 + row0) * 512 + kc;
    const bf16* gA1 = W + (size_t)(c0 + row0 + 64) * 512 + kc;
    const bf16* gB0 = O + ((size_t)b * NPIX_ + pB0) * 512 + kc;
    const bf16* gB1 = O + ((size_t)b * NPIX_ + pB1) * 512 + kc;
    char* lA = (char*)sA + tid * 16;
    char* lB = (char*)sB + tid * 16;

    int lane = tid & 63, wv = tid >> 6;
    int wm = (wv >> 1) * 64;
    int wn = (wv & 1) * 64;
    int col16 = lane & 15, quad = lane >> 4;

    f32x4 acc[4][4] = {};
    for (int k0 = 0; k0 < 512; k0 += 32) {
        async16(gA0, lA);
        async16(gA1, lA + 4096);
        async16(gB0, lB);
        async16(gB1, lB + 4096);
        gA0 += 32; gA1 += 32; gB0 += 32; gB1 += 32;
        __syncthreads();
        bfv8 af[4], bfr[4];
#pragma unroll
        for (int mt = 0; mt < 4; ++mt)
            af[mt] = *(const bfv8*)(sA + (wm + mt * 16 + col16) * 32 + quad * 8);
#pragma unroll
        for (int nt = 0; nt < 4; ++nt)
            bfr[nt] = *(const bfv8*)(sB + (wn + nt * 16 + col16) * 32 + quad * 8);
#pragma unroll
        for (int mt = 0; mt < 4; ++mt)
#pragma unroll
            for (int nt = 0; nt < 4; ++nt)
                acc[mt][nt] = __builtin_amdgcn_mfma_f32_16x16x32_bf16(
                    af[mt], bfr[nt], acc[mt][nt], 0, 0, 0);
        __syncthreads();
    }
#pragma unroll
    for (int mt = 0; mt < 4; ++mt) {
#pragma unroll
        for (int r = 0; r < 4; ++r) {
            int ch = c0 + wm + mt * 16 + quad * 4 + r;
            float bc = bias[ch];
#pragma unroll
            for (int nt = 0; nt < 4; ++nt) {
                int p = p0 + wn + nt * 16 + col16;
                if (p < NPIX_)
                    out[((size_t)b * C_ + ch) * NPIX_ + p] = acc[mt][nt][r] + bc;
            }
        }
    }
}

// ---------------------------------------------------------------------------
extern "C" void kernel_launch(void* const* d_in, const int* in_sizes, int n_in,
                              void* d_out, int out_size, void* d_ws, size_t ws_size,
                              hipStream_t stream) {
    (void)in_sizes; (void)n_in; (void)out_size; (void)ws_size;
    const float* x     = (const float*)d_in[0];
    const float* pos   = (const float*)d_in[19];
    const float* out_w = (const float*)d_in[20];
    const float* out_b = (const float*)d_in[21];

    size_t tElems = (size_t)B_ * NPIX_ * C_;        // 12.845M
    size_t qElems = (size_t)B_ * INNER_ * NPIX_;    // 25.69M
    bf16* tq = (bf16*)d_ws;                         // t's: [3][B][pix][256]
    bf16* q  = tq + 3 * tElems;                     // qkv: [3][B][h][w][49][64]
    bf16* o  = tq;                                  // aliases tq+tk (dead by attn)
    float* wf = (float*)(q + 3 * qElems);           // [3][256][12] fp32
    bf16* wq = (bf16*)(wf + 3 * 256 * 12);          // [4][512*256] bf16 weights
    bf16* wo = wq + 3 * (INNER_ * C_);
    float* biasf = (float*)(wo + C_ * INNER_);      // [8][4][64][16] fp32

    dim3 blk(256);
    dim3 gDw(HW_, 4, B_);                           // 56 x 4 x 16
    dim3 gQkv(4, 25, 48);                           // swizzled in-kernel (4800)
    dim3 gOut(2, 25, 16);                           // swizzled in-kernel (800)

    setup_kernel<<<2059, blk, 0, stream>>>(
        (const float*)d_in[6], (const float*)d_in[12], (const float*)d_in[18],
        out_w, wq,
        (const float*)d_in[1],  (const float*)d_in[2],  (const float*)d_in[3],
        (const float*)d_in[4],  (const float*)d_in[5],
        (const float*)d_in[7],  (const float*)d_in[8],  (const float*)d_in[9],
        (const float*)d_in[10], (const float*)d_in[11],
        (const float*)d_in[13], (const float*)d_in[14], (const float*)d_in[15],
        (const float*)d_in[16], (const float*)d_in[17], wf,
        pos, biasf);

    dwbn3_kernel<<<gDw, blk, 0, stream>>>(x, wf, tq, tq + tElems, tq + 2 * tElems);
    gemm_qkv_mfma<<<gQkv, blk, 0, stream>>>(wq, tq, q);
    attn_mfma<<<B_ * HEADS_ * NWIN_, blk, 0, stream>>>(
        q, q + qElems, q + 2 * qElems, biasf, o);
    gemm_out_mfma<<<gOut, blk, 0, stream>>>(wo, o, out_b, (float*)d_out);
}